// Round 1
// baseline (407.556 us; speedup 1.0000x reference)
//
#include <hip/hip_runtime.h>
#include <hip/hip_cooperative_groups.h>

namespace cg = cooperative_groups;

#define C_IN  128
#define C_RES 64
#define D     512
#define DD    (D * D)          // 262144 floats per c-slice
#define NC4   (DD / 4)         // 65536 float4 chunks per (o,i) plane

// Column-sum of 64 c-slices: float4 chunk at stride NC4 (1 MB).
__device__ __forceinline__ float4 colsum64(const float4* __restrict__ p) {
    float4 acc = make_float4(0.f, 0.f, 0.f, 0.f);
#pragma unroll 16
    for (int c = 0; c < 64; ++c) {
        float4 w = p[(size_t)c * NC4];
        acc.x += w.x; acc.y += w.y; acc.z += w.z; acc.w += w.w;
    }
    return acc;
}

// One cooperative kernel, 384 blocks x 256 threads (<=2 blocks/CU co-resident).
// Phase 1: balanced colsums (every thread exactly 128 float4 loads) + zero diff.
//   Jobs: W1 c[0,64) -> S1lo, W1 c[64,128) -> S1hi, W2 c[0,64) -> S2.
//   196608 jobs of 64 loads over 98304 threads = 2 jobs/thread, coalesced.
// Phase 2: 128 blocks, 8 cols each. Blocks 0..63: stage-1 argmax over
//   S1lo+S1hi + scatter diff1 += W1[c,n,i]*relu(x). Blocks 64..127: stage-2
//   argmax over S2 (FULL o-range now) -> node2 + gather w2v = W2[c,n,i].
// Phase 3: x2 = relu(bc1 + Wc1*diff1); diff2[c,node2[i]] += w2v*x2.
// Phase 4: out = relu(x) + bc2 + Wc2*diff2.
__global__ void fused_kernel(const float* __restrict__ x,
                             const float* __restrict__ W1,
                             const float* __restrict__ Wc1,
                             const float* __restrict__ bc1,
                             const float* __restrict__ W2,
                             const float* __restrict__ Wc2,
                             const float* __restrict__ bc2,
                             float* __restrict__ out,
                             float* __restrict__ ws) {
    cg::grid_group grid = cg::this_grid();

    // Workspace carve-up (diff1|diff2 contiguous for the fused zeroing).
    float* S1lo  = ws;                     // 262144
    float* S1hi  = S1lo + DD;              // 262144
    float* S2    = S1hi + DD;              // 262144
    float* diff1 = S2 + DD;                // 65536
    float* diff2 = diff1 + C_IN * D;       // 32768
    float* w2v   = diff2 + C_RES * D;      // 32768
    int*   node2 = (int*)(w2v + C_RES * D);// 512

    const int tid = threadIdx.x;
    const int bid = blockIdx.x;
    const int u   = bid * 256 + tid;       // 0 .. 98303

    __shared__ float lv[256];
    __shared__ int   li[256];
    __shared__ int   node_s[8];

    // ---------------- Phase 1 ----------------
    {
        // job A: u<NC4 -> W1lo chunk u; else W1hi chunk u-NC4 (0..32767)
        if (u < NC4) {
            ((float4*)S1lo)[u] = colsum64((const float4*)W1 + u);
        } else {
            int t = u - NC4;                              // 0..32767
            ((float4*)S1hi)[t] =
                colsum64((const float4*)W1 + (size_t)64 * NC4 + t);
        }
        // job B: u<NC4/2 -> W1hi chunk u+NC4/2; else W2 chunk u-NC4/2 (full S2)
        if (u < NC4 / 2) {
            int t = u + NC4 / 2;                          // 32768..65535
            ((float4*)S1hi)[t] =
                colsum64((const float4*)W1 + (size_t)64 * NC4 + t);
        } else {
            int t = u - NC4 / 2;                          // 0..65535
            ((float4*)S2)[t] = colsum64((const float4*)W2 + t);
        }
        diff1[u] = 0.f;   // zeroes diff1 (65536) + diff2 (32768), contiguous
    }
    grid.sync();

    // ---------------- Phase 2 ----------------
    if (bid < 128) {
        const bool st1 = bid < 64;
        const int  i0  = (bid & 63) * 8;
        const int  il  = tid & 7;
        const int  ol  = tid >> 3;                        // 0..31
        float best = -__builtin_inff();
        int   bidx = D;                                   // > any valid o
#pragma unroll
        for (int k = 0; k < 16; ++k) {
            int o = ol + (k << 5);                        // ascending per thread
            float v = st1 ? (S1lo[o * D + i0 + il] + S1hi[o * D + i0 + il])
                          : S2[o * D + i0 + il];
            if (v > best) { best = v; bidx = o; }         // strict >: first wins
        }
        lv[tid] = best; li[tid] = bidx;
        __syncthreads();
        for (int s = 128; s >= 8; s >>= 1) {
            if (tid < s) {
                float v2 = lv[tid + s]; int i2 = li[tid + s];
                if (v2 > lv[tid] || (v2 == lv[tid] && i2 < li[tid])) {
                    lv[tid] = v2; li[tid] = i2;
                }
            }
            __syncthreads();
        }
        if (tid < 8) {
            node_s[tid] = li[tid];
            if (!st1) node2[i0 + tid] = li[tid];
        }
        __syncthreads();

        if (st1) {
            // 128 c x 8 i = 1024 ops, 4 rounds
            for (int idx = tid; idx < C_IN * 8; idx += 256) {
                int ii = idx & 7;
                int c  = idx >> 3;
                int i  = i0 + ii;
                int n  = node_s[ii];
                float xv = fmaxf(x[c * D + i], 0.f);
                float w  = W1[(size_t)c * DD + (size_t)n * D + i];
                atomicAdd(&diff1[c * D + n], w * xv);
            }
        } else {
            // 64 c x 8 i = 512 ops, 2 rounds
            for (int idx = tid; idx < C_RES * 8; idx += 256) {
                int ii = idx & 7;
                int c  = idx >> 3;
                int i  = i0 + ii;
                int n  = node_s[ii];
                w2v[c * D + i] = W2[(size_t)c * DD + (size_t)n * D + i];
            }
        }
    }
    grid.sync();

    // ---------------- Phase 3 ----------------
    if (bid < 128) {
        const int c = bid >> 1;                           // 0..63
        const int i = ((bid & 1) << 8) + tid;
        if (tid < C_IN) lv[tid] = Wc1[c * C_IN + tid];
        __syncthreads();
        float acc = bc1[c];
#pragma unroll 8
        for (int cc = 0; cc < C_IN; ++cc)
            acc += lv[cc] * diff1[cc * D + i];
        float x2 = fmaxf(acc, 0.f);
        int n = node2[i];
        atomicAdd(&diff2[c * D + n], w2v[c * D + i] * x2);
    }
    grid.sync();

    // ---------------- Phase 4 ----------------
    if (bid < 256) {
        const int o = bid >> 1;                           // 0..127
        const int d = ((bid & 1) << 8) + tid;
        if (tid < C_RES) lv[tid] = Wc2[o * C_RES + tid];
        __syncthreads();
        float acc = bc2[o];
#pragma unroll 8
        for (int c = 0; c < C_RES; ++c)
            acc += lv[c] * diff2[c * D + d];
        out[o * D + d] = acc + fmaxf(x[o * D + d], 0.f);
    }
}

extern "C" void kernel_launch(void* const* d_in, const int* in_sizes, int n_in,
                              void* d_out, int out_size, void* d_ws, size_t ws_size,
                              hipStream_t stream) {
    const float* x   = (const float*)d_in[0];   // (1, 128, 512)
    const float* W1  = (const float*)d_in[1];   // (128, 512, 512)
    const float* Wc1 = (const float*)d_in[2];   // (64, 128)
    const float* bc1 = (const float*)d_in[3];   // (64,)
    const float* W2  = (const float*)d_in[4];   // (64, 512, 512)
    const float* Wc2 = (const float*)d_in[5];   // (128, 64)
    const float* bc2 = (const float*)d_in[6];   // (128,)
    float* out = (float*)d_out;                 // (1, 128, 512) fp32
    float* ws  = (float*)d_ws;

    void* args[] = {(void*)&x, (void*)&W1, (void*)&Wc1, (void*)&bc1,
                    (void*)&W2, (void*)&Wc2, (void*)&bc2, (void*)&out, (void*)&ws};
    hipLaunchCooperativeKernel((const void*)fused_kernel, dim3(384), dim3(256),
                               args, 0, stream);
}

// Round 2
// 267.934 us; speedup vs baseline: 1.5211x; 1.5211x over previous
//
#include <hip/hip_runtime.h>

#define C_IN  128
#define C_RES 64
#define D     512
#define DD    (D * D)          // 262144 floats per c-slice
#define NC4   (DD / 4)         // 65536 float4 chunks per (o,i) plane

// ---------------------------------------------------------------------------
// K1: 1536 blocks x 256 = 393216 threads. Six partial-sum planes, each a
// 32-channel column sum: planes 0..3 cover W1 c[32p,32p+32), planes 4..5
// cover W2. Every thread does exactly 32 coalesced float4 loads + 1 store.
// 24 waves/CU (6/SIMD) vs the old 6/CU -> hides HBM latency.
// Also zeroes diff1|diff2 (98304 floats, contiguous).
// ---------------------------------------------------------------------------
__global__ void sum_zero_kernel(const float* __restrict__ W1,
                                const float* __restrict__ W2,
                                float* __restrict__ Sp,       // 6*DD floats
                                float* __restrict__ diff_zero) {
    int t = blockIdx.x * 256 + threadIdx.x;       // 0 .. 393215
    int plane = t >> 16;                          // 0..5
    int chunk = t & 0xFFFF;                       // 0..65535
    const float4* p = (plane < 4)
        ? (const float4*)W1 + (size_t)plane * 32 * NC4 + chunk
        : (const float4*)W2 + (size_t)(plane - 4) * 32 * NC4 + chunk;
    float4 acc = make_float4(0.f, 0.f, 0.f, 0.f);
#pragma unroll 16
    for (int c = 0; c < 32; ++c) {
        float4 w = p[(size_t)c * NC4];
        acc.x += w.x; acc.y += w.y; acc.z += w.z; acc.w += w.w;
    }
    ((float4*)Sp)[t] = acc;
    if (t < (C_IN + C_RES) * D) diff_zero[t] = 0.f;   // diff1 + diff2
}

// ---------------------------------------------------------------------------
// K2: 256 blocks x 256, 4 columns per block. Blocks 0..127: stage-1 argmax
// over sum of 4 W1-planes, then scatter diff1[c,n] += W1[c,n,i]*relu(x[c,i]).
// Blocks 128..255: stage-2 argmax over sum of 2 W2-planes (FULL o range),
// write node2, pre-gather w2v[c,i] = W2[c,n_i,i].
// Tie-break = first (smallest o), matching jnp.argmax.
// ---------------------------------------------------------------------------
__global__ void argmax_scatter_kernel(const float* __restrict__ Sp,
                                      const float* __restrict__ W1,
                                      const float* __restrict__ W2,
                                      const float* __restrict__ x,
                                      float* __restrict__ diff1,
                                      float* __restrict__ w2v,
                                      int* __restrict__ node2) {
    __shared__ float lv[256];
    __shared__ int   li[256];
    __shared__ int   node_s[4];

    const int  tid = threadIdx.x;
    const bool st1 = blockIdx.x < 128;
    const int  i0  = (blockIdx.x & 127) * 4;
    const int  il  = tid & 3;
    const int  ol  = tid >> 2;                    // 0..63
    const float* __restrict__ S1p = Sp;
    const float* __restrict__ S2p = Sp + (size_t)4 * DD;

    float best = -__builtin_inff();
    int   bidx = D;                               // > any valid o
#pragma unroll
    for (int k = 0; k < 8; ++k) {
        int o   = ol + (k << 6);                  // ascending per thread
        int off = o * D + i0 + il;
        float v;
        if (st1)
            v = S1p[off] + S1p[DD + off] + S1p[2 * DD + off] + S1p[3 * DD + off];
        else
            v = S2p[off] + S2p[DD + off];
        if (v > best) { best = v; bidx = o; }     // strict >: first wins
    }
    lv[tid] = best; li[tid] = bidx;
    __syncthreads();
    for (int s = 128; s >= 4; s >>= 1) {
        if (tid < s) {
            float v2 = lv[tid + s]; int i2 = li[tid + s];
            if (v2 > lv[tid] || (v2 == lv[tid] && i2 < li[tid])) {
                lv[tid] = v2; li[tid] = i2;
            }
        }
        __syncthreads();
    }
    if (tid < 4) {
        node_s[tid] = li[tid];
        if (!st1) node2[i0 + tid] = li[tid];
    }
    __syncthreads();

    if (st1) {
        // 128 c x 4 i = 512 ops, 2 rounds
        for (int idx = tid; idx < C_IN * 4; idx += 256) {
            int ii = idx & 3;
            int c  = idx >> 2;
            int i  = i0 + ii;
            int n  = node_s[ii];
            float xv = fmaxf(x[c * D + i], 0.f);
            float w  = W1[(size_t)c * DD + (size_t)n * D + i];
            atomicAdd(&diff1[c * D + n], w * xv);
        }
    } else {
        // 64 c x 4 i = 256 ops, 1 round
        for (int idx = tid; idx < C_RES * 4; idx += 256) {
            int ii = idx & 3;
            int c  = idx >> 2;
            int i  = i0 + ii;
            int n  = node_s[ii];
            w2v[c * D + i] = W2[(size_t)c * DD + (size_t)n * D + i];
        }
    }
}

// ---------------------------------------------------------------------------
// K3: x2 = relu(bc1[c] + sum_cc Wc1[c,cc]*diff1[cc,i]);
//     diff2[c, node2[i]] += w2v[c,i] * x2
// 128 blocks x 256; c = blockIdx>>1, i = (blockIdx&1)*256+tid.
// ---------------------------------------------------------------------------
__global__ void conv1_scatter2_kernel(const float* __restrict__ Wc1,
                                      const float* __restrict__ bc1,
                                      const float* __restrict__ diff1,
                                      const float* __restrict__ w2v,
                                      const int* __restrict__ node2,
                                      float* __restrict__ diff2) {
    __shared__ float wc[C_IN];
    const int c = blockIdx.x >> 1;                // 0..63
    const int i = ((blockIdx.x & 1) << 8) + threadIdx.x;
    if (threadIdx.x < C_IN) wc[threadIdx.x] = Wc1[c * C_IN + threadIdx.x];
    __syncthreads();

    float acc = bc1[c];
#pragma unroll 8
    for (int cc = 0; cc < C_IN; ++cc)
        acc += wc[cc] * diff1[cc * D + i];        // lanes = consecutive i
    float x2 = fmaxf(acc, 0.f);
    int n = node2[i];
    atomicAdd(&diff2[c * D + n], w2v[c * D + i] * x2);
}

// ---------------------------------------------------------------------------
// K4: out[o,d] = relu(x[o,d]) + bc2[o] + sum_c Wc2[o,c]*diff2[c,d]
// 256 blocks x 256; o = blockIdx>>1, d = (blockIdx&1)*256+tid.
// ---------------------------------------------------------------------------
__global__ void final_kernel(const float* __restrict__ Wc2,
                             const float* __restrict__ bc2,
                             const float* __restrict__ diff2,
                             const float* __restrict__ x,
                             float* __restrict__ out) {
    __shared__ float wc[C_RES];
    const int o = blockIdx.x >> 1;                // 0..127
    const int d = ((blockIdx.x & 1) << 8) + threadIdx.x;
    if (threadIdx.x < C_RES) wc[threadIdx.x] = Wc2[o * C_RES + threadIdx.x];
    __syncthreads();

    float acc = bc2[o];
#pragma unroll 8
    for (int c = 0; c < C_RES; ++c)
        acc += wc[c] * diff2[c * D + d];
    out[o * D + d] = acc + fmaxf(x[o * D + d], 0.f);
}

extern "C" void kernel_launch(void* const* d_in, const int* in_sizes, int n_in,
                              void* d_out, int out_size, void* d_ws, size_t ws_size,
                              hipStream_t stream) {
    const float* x   = (const float*)d_in[0];   // (1, 128, 512)
    const float* W1  = (const float*)d_in[1];   // (128, 512, 512)
    const float* Wc1 = (const float*)d_in[2];   // (64, 128)
    const float* bc1 = (const float*)d_in[3];   // (64,)
    const float* W2  = (const float*)d_in[4];   // (64, 512, 512)
    const float* Wc2 = (const float*)d_in[5];   // (128, 64)
    const float* bc2 = (const float*)d_in[6];   // (128,)
    float* out = (float*)d_out;                 // (1, 128, 512) fp32

    // Workspace carve-up (floats); diff1|diff2 contiguous for K1's zeroing.
    float* ws    = (float*)d_ws;
    float* Sp    = ws;                          // 6 * 262144 partial planes
    float* diff1 = Sp + (size_t)6 * DD;         // 65536
    float* diff2 = diff1 + C_IN * D;            // 32768 (contiguous after diff1)
    float* w2v   = diff2 + C_RES * D;           // 32768
    int*   node2 = (int*)(w2v + C_RES * D);     // 512

    // K1: stream W1+W2 (201 MB) into 6 partial planes + zero diff1/diff2
    sum_zero_kernel<<<1536, 256, 0, stream>>>(W1, W2, Sp, diff1);
    // K2: argmax both stages (summing partials) + stage-1 scatter + W2 gather
    argmax_scatter_kernel<<<256, 256, 0, stream>>>(Sp, W1, W2, x,
                                                   diff1, w2v, node2);
    // K3: stage-1 1x1 conv (+bias,relu) fused with stage-2 scatter
    conv1_scatter2_kernel<<<128, 256, 0, stream>>>(Wc1, bc1, diff1, w2v,
                                                   node2, diff2);
    // K4: stage-2 1x1 conv + bias + residual relu(x)
    final_kernel<<<256, 256, 0, stream>>>(Wc2, bc2, diff2, x, out);
}